// Round 3
// baseline (119.696 us; speedup 1.0000x reference)
//
#include <hip/hip_runtime.h>

// Lin2d: x_final = x @ (linMt)^N.  N-step linear recurrence == one matrix
// power (binary exponentiation, fp32) + one streaming pass over x.
// Traffic: 64 MiB read + 64 MiB write -> ~21.3 us floor at 6.29 TB/s
// (measured float4-copy ceiling).
//
// Ordering trick: x loads are independent of the matrix power, but a
// dynamic-trip-count while loop before them blocks hoisting. So: load FIRST,
// then compute the power while loads are in flight, then FMA + store.
// Non-temporal hints: 128 MiB streamed, no reuse — don't thrash L2.

// Native clang vector type: __builtin_nontemporal_* requires it (HIP's
// float4 is a class and is rejected).
typedef float f4 __attribute__((ext_vector_type(4)));

__global__ __launch_bounds__(256)
void lin2d_apply(const float* __restrict__ x,
                 const float* __restrict__ linMt,
                 const int* __restrict__ Nptr,
                 float* __restrict__ out,
                 long long n4, long long ntail_pairs)
{
    const f4* __restrict__ xin = (const f4*)x;
    f4* __restrict__ o = (f4*)out;

    // 2 f4 per thread, block-strided so every wave load is a fully
    // coalesced 16 B/lane burst: [blk*512 + tid] and [blk*512 + 256 + tid].
    long long i0 = (long long)blockIdx.x * 512 + threadIdx.x;
    long long i1 = i0 + 256;
    bool h0 = i0 < n4, h1 = i1 < n4;

    f4 v0 = {0.f, 0.f, 0.f, 0.f}, v1 = {0.f, 0.f, 0.f, 0.f};
    if (h0) v0 = __builtin_nontemporal_load(&xin[i0]);
    if (h1) v1 = __builtin_nontemporal_load(&xin[i1]);

    // A = linMt row-major 2x2.  y = x @ A  =>  y_j = x0*A[0][j] + x1*A[1][j].
    // M = A^N via binary exponentiation (~100 FMAs, overlapped with the
    // in-flight vector loads above).
    float b00 = linMt[0], b01 = linMt[1];
    float b10 = linMt[2], b11 = linMt[3];
    unsigned e = (unsigned)Nptr[0];
    float r00 = 1.f, r01 = 0.f, r10 = 0.f, r11 = 1.f;
    while (e) {
        if (e & 1u) {
            float t00 = r00*b00 + r01*b10;
            float t01 = r00*b01 + r01*b11;
            float t10 = r10*b00 + r11*b10;
            float t11 = r10*b01 + r11*b11;
            r00 = t00; r01 = t01; r10 = t10; r11 = t11;
        }
        e >>= 1;
        if (e) {
            float t00 = b00*b00 + b01*b10;
            float t01 = b00*b01 + b01*b11;
            float t10 = b10*b00 + b11*b10;
            float t11 = b10*b01 + b11*b11;
            b00 = t00; b01 = t01; b10 = t10; b11 = t11;
        }
    }

    if (h0) {
        f4 w;
        w.x = v0.x * r00 + v0.y * r10;
        w.y = v0.x * r01 + v0.y * r11;
        w.z = v0.z * r00 + v0.w * r10;
        w.w = v0.z * r01 + v0.w * r11;
        __builtin_nontemporal_store(w, &o[i0]);
    }
    if (h1) {
        f4 w;
        w.x = v1.x * r00 + v1.y * r10;
        w.y = v1.x * r01 + v1.y * r11;
        w.z = v1.z * r00 + v1.w * r10;
        w.w = v1.z * r01 + v1.w * r11;
        __builtin_nontemporal_store(w, &o[i1]);
    }

    // Tail (total floats not divisible by 4) — scalar, one thread.
    if (blockIdx.x == 0 && threadIdx.x == 0) {
        for (long long p = 0; p < ntail_pairs; ++p) {
            long long base = n4 * 4 + p * 2;
            float x0 = x[base], x1 = x[base + 1];
            out[base]     = x0 * r00 + x1 * r10;
            out[base + 1] = x0 * r01 + x1 * r11;
        }
    }
}

extern "C" void kernel_launch(void* const* d_in, const int* in_sizes, int n_in,
                              void* d_out, int out_size, void* d_ws, size_t ws_size,
                              hipStream_t stream) {
    const float* x     = (const float*)d_in[0];   // (B, 2) fp32, flat
    const float* linMt = (const float*)d_in[1];   // 2x2 fp32
    const int*   N     = (const int*)d_in[2];     // scalar int as 1-elem array
    float* out = (float*)d_out;

    long long total = (long long)in_sizes[0];     // B*2 floats
    long long n4 = total / 4;                     // float4 chunks
    long long ntail_pairs = (total - n4 * 4) / 2;

    // Exact-size launch: 2 f4 per thread -> n4/512 blocks of 256.
    int blocks = (int)((n4 + 511) / 512);
    if (blocks < 1) blocks = 1;
    lin2d_apply<<<blocks, 256, 0, stream>>>(x, linMt, N, out, n4, ntail_pairs);
}

// Round 4
// 112.860 us; speedup vs baseline: 1.0606x; 1.0606x over previous
//
#include <hip/hip_runtime.h>

// Lin2d: x_final = x @ (linMt)^N.  N-step linear recurrence == one matrix
// power (binary exponentiation, fp32) + one streaming pass over x.
// Traffic: 64 MiB read + 64 MiB write -> ~21.3 us floor at 6.29 TB/s HBM;
// potentially less if the harness's x-restore copy leaves x LLC-resident.
//
// R2->R3 post-mortem: non-temporal hints REGRESSED (114.5 -> 119.7 us total).
// The harness restores x (64 MiB d2d) and poisons out right before the
// kernel, so both buffers are likely Infinity-Cache-resident; nt hints
// forfeit those hits. Plain cached loads/stores here.
//
// Ordering trick kept: x loads are independent of the matrix power, but the
// dynamic-trip-count while loop blocks hoisting — so load FIRST, compute the
// power while loads are in flight, then FMA + store.

typedef float f4 __attribute__((ext_vector_type(4)));

__global__ __launch_bounds__(256)
void lin2d_apply(const float* __restrict__ x,
                 const float* __restrict__ linMt,
                 const int* __restrict__ Nptr,
                 float* __restrict__ out,
                 long long n4, long long ntail_pairs)
{
    const f4* __restrict__ xin = (const f4*)x;
    f4* __restrict__ o = (f4*)out;

    // 2 f4 per thread, block-strided: [blk*512 + tid] and [blk*512 + 256 + tid]
    // -> every wave load is a fully coalesced 16 B/lane burst.
    long long i0 = (long long)blockIdx.x * 512 + threadIdx.x;
    long long i1 = i0 + 256;
    bool h0 = i0 < n4, h1 = i1 < n4;

    f4 v0 = {0.f, 0.f, 0.f, 0.f}, v1 = {0.f, 0.f, 0.f, 0.f};
    if (h0) v0 = xin[i0];
    if (h1) v1 = xin[i1];

    // A = linMt row-major 2x2.  y = x @ A  =>  y_j = x0*A[0][j] + x1*A[1][j].
    // M = A^N via binary exponentiation (~100 FMAs, overlapped with the
    // in-flight vector loads above).
    float b00 = linMt[0], b01 = linMt[1];
    float b10 = linMt[2], b11 = linMt[3];
    unsigned e = (unsigned)Nptr[0];
    float r00 = 1.f, r01 = 0.f, r10 = 0.f, r11 = 1.f;
    while (e) {
        if (e & 1u) {
            float t00 = r00*b00 + r01*b10;
            float t01 = r00*b01 + r01*b11;
            float t10 = r10*b00 + r11*b10;
            float t11 = r10*b01 + r11*b11;
            r00 = t00; r01 = t01; r10 = t10; r11 = t11;
        }
        e >>= 1;
        if (e) {
            float t00 = b00*b00 + b01*b10;
            float t01 = b00*b01 + b01*b11;
            float t10 = b10*b00 + b11*b10;
            float t11 = b10*b01 + b11*b11;
            b00 = t00; b01 = t01; b10 = t10; b11 = t11;
        }
    }

    if (h0) {
        f4 w;
        w.x = v0.x * r00 + v0.y * r10;
        w.y = v0.x * r01 + v0.y * r11;
        w.z = v0.z * r00 + v0.w * r10;
        w.w = v0.z * r01 + v0.w * r11;
        o[i0] = w;
    }
    if (h1) {
        f4 w;
        w.x = v1.x * r00 + v1.y * r10;
        w.y = v1.x * r01 + v1.y * r11;
        w.z = v1.z * r00 + v1.w * r10;
        w.w = v1.z * r01 + v1.w * r11;
        o[i1] = w;
    }

    // Tail (total floats not divisible by 4) — scalar, one thread.
    if (blockIdx.x == 0 && threadIdx.x == 0) {
        for (long long p = 0; p < ntail_pairs; ++p) {
            long long base = n4 * 4 + p * 2;
            float x0 = x[base], x1 = x[base + 1];
            out[base]     = x0 * r00 + x1 * r10;
            out[base + 1] = x0 * r01 + x1 * r11;
        }
    }
}

extern "C" void kernel_launch(void* const* d_in, const int* in_sizes, int n_in,
                              void* d_out, int out_size, void* d_ws, size_t ws_size,
                              hipStream_t stream) {
    const float* x     = (const float*)d_in[0];   // (B, 2) fp32, flat
    const float* linMt = (const float*)d_in[1];   // 2x2 fp32
    const int*   N     = (const int*)d_in[2];     // scalar int as 1-elem array
    float* out = (float*)d_out;

    long long total = (long long)in_sizes[0];     // B*2 floats
    long long n4 = total / 4;                     // float4 chunks
    long long ntail_pairs = (total - n4 * 4) / 2;

    // Exact-size launch: 2 f4 per thread -> n4/512 blocks of 256.
    int blocks = (int)((n4 + 511) / 512);
    if (blocks < 1) blocks = 1;
    lin2d_apply<<<blocks, 256, 0, stream>>>(x, linMt, N, out, n4, ntail_pairs);
}